// Round 8
// baseline (974.404 us; speedup 1.0000x reference)
//
#include <hip/hip_runtime.h>

// Problem constants (B=2, L=2048, H=1024, NH=16, D=64, M=2048)
// scores = (Q K^T + Q·E[l-r+M-1] + K·E[l-r+M-1]) / 8 + mask; softmax; @V

typedef float f32x4 __attribute__((ext_vector_type(4)));
typedef short bf16x8 __attribute__((ext_vector_type(8)));

__device__ __forceinline__ unsigned short f2bf(float x){
  unsigned u = __float_as_uint(x);
  u += 0x7fffu + ((u>>16)&1u);           // round-to-nearest-even
  return (unsigned short)(u>>16);
}
__device__ __forceinline__ float bf2f(unsigned short s){
  return __uint_as_float(((unsigned)s)<<16);
}
__device__ __forceinline__ unsigned pk2(float a, float b){
  return (unsigned)f2bf(a) | ((unsigned)f2bf(b)<<16);
}

// ---- kernel: fp32 -> bf16 (X: 4096x1024) ----
__global__ void k_cvt_x(const float* __restrict__ x, unsigned short* __restrict__ o){
  int i = (blockIdx.x*256 + threadIdx.x)*4;
  float4 v = *(const float4*)(x + i);
  ushort4 r; r.x=f2bf(v.x); r.y=f2bf(v.y); r.z=f2bf(v.z); r.w=f2bf(v.w);
  *(ushort4*)(o + i) = r;
}

// ---- kernel: dist_emb fp32 [4095][64] -> bf16 [4096][64], row 4095 zeroed ----
__global__ void k_cvt_e(const float* __restrict__ e, unsigned short* __restrict__ o){
  int i = (blockIdx.x*256 + threadIdx.x)*4;
  ushort4 r;
  if (i < 4095*64){
    float4 v = *(const float4*)(e + i);
    r.x=f2bf(v.x); r.y=f2bf(v.y); r.z=f2bf(v.z); r.w=f2bf(v.w);
  } else { r.x=0; r.y=0; r.z=0; r.w=0; }
  *(ushort4*)(o + i) = r;
}

// ---- kernel: W [k][n] fp32 -> Wt [w][n][k] bf16 (transpose+convert) ----
__global__ void k_wt(const float* __restrict__ Wq, const float* __restrict__ Wk,
                     const float* __restrict__ Wv, unsigned short* __restrict__ wt){
  int w = blockIdx.z;
  const float* W = (w==0)?Wq:((w==1)?Wk:Wv);
  __shared__ float t[32][33];
  int k0 = blockIdx.x*32, n0 = blockIdx.y*32;
  int tx = threadIdx.x&31, ty = threadIdx.x>>5;   // ty in [0,8)
  for(int j=0;j<4;j++) t[ty+8*j][tx] = W[(k0+ty+8*j)*1024 + n0+tx];
  __syncthreads();
  unsigned short* o = wt + w*1048576;
  for(int j=0;j<4;j++) o[(n0+ty+8*j)*1024 + k0+tx] = f2bf(t[tx][ty+8*j]);
}

// ---- kernel: fused QKV projection GEMM (bf16 MFMA), 128x128 tile ----
// Q,K stored bf16 [bh][l][d]; V stored transposed bf16 [bh][d][l]
__global__ __launch_bounds__(256,2) void k_proj(const unsigned short* __restrict__ xb,
      const unsigned short* __restrict__ wt,
      const float* __restrict__ bq, const float* __restrict__ bk, const float* __restrict__ bv,
      unsigned short* __restrict__ Qo, unsigned short* __restrict__ Ko, unsigned short* __restrict__ Vt){
  __shared__ char sm[32768];
  char* sA = sm; char* sB = sm + 16384;          // [128 rows][64 k] bf16, swizzled
  int tid = threadIdx.x, lane = tid&63, wid = tid>>6;
  int g = lane>>4, cl = lane&15;
  int m0 = blockIdx.x*128;
  int wsel = blockIdx.y>>3; int n0 = (blockIdx.y&7)*128;
  const unsigned short* wp = wt + wsel*1048576;
  int wr = (wid>>1)*64, wc = (wid&1)*64;
  f32x4 acc[4][4] = {};
  for(int ks=0; ks<16; ks++){
    int k0 = ks*64;
    for(int it=0; it<4; it++){
      int ch = tid + it*256;
      int row = ch>>3; int bc = (ch&7)*16;
      uint4 va = *(const uint4*)((const char*)xb + ((size_t)(m0+row)*1024 + k0)*2 + bc);
      *(uint4*)(sA + row*128 + (bc ^ ((row&7)<<4))) = va;
      uint4 vb = *(const uint4*)((const char*)wp + ((size_t)(n0+row)*1024 + k0)*2 + bc);
      *(uint4*)(sB + row*128 + (bc ^ ((row&7)<<4))) = vb;
    }
    __syncthreads();
    for(int kc=0;kc<2;kc++){
      bf16x8 af[4], bfr[4];
      for(int i=0;i<4;i++){
        int ra = wr + i*16 + cl;
        af[i] = *(const bf16x8*)(sA + ra*128 + ((kc*64 + g*16) ^ ((ra&7)<<4)));
        int rb = wc + i*16 + cl;
        bfr[i] = *(const bf16x8*)(sB + rb*128 + ((kc*64 + g*16) ^ ((rb&7)<<4)));
      }
      for(int i=0;i<4;i++)
        for(int j=0;j<4;j++)
          acc[i][j] = __builtin_amdgcn_mfma_f32_16x16x32_bf16(af[i], bfr[j], acc[i][j], 0,0,0);
    }
    __syncthreads();
  }
  const float* bias = (wsel==0)?bq:((wsel==1)?bk:bv);
  for(int j=0;j<4;j++){
    int n = n0 + wc + j*16 + cl;
    float bb = bias[n];
    int h = n>>6, d = n&63;
    for(int i=0;i<4;i++){
      int mbase = m0 + wr + i*16 + g*4;           // 4 consecutive rows (reg 0..3)
      int b = mbase>>11; int l = mbase&2047; int bh = b*16 + h;
      if (wsel==2){
        uint2 p; p.x = pk2(acc[i][j][0]+bb, acc[i][j][1]+bb);
        p.y = pk2(acc[i][j][2]+bb, acc[i][j][3]+bb);
        *(uint2*)((char*)Vt + ((size_t)(bh*64 + d)*2048 + l)*2) = p;
      } else {
        unsigned short* O = (wsel==0)?Qo:Ko;
        for(int r=0;r<4;r++)
          O[(size_t)(bh*2048 + (l+r))*64 + d] = f2bf(acc[i][j][r]+bb);
      }
    }
  }
}

// ---- kernel: fused flash attention with relative_key_query terms ----
// grid: 1024 = bh(32) x ltile(32); block 256 (4 waves, each owns 16 l-rows)
// LDS 40KB -> 4 blocks/CU (exactly fills 160KB; grid = exactly 4 blocks/CU).
// KdT overlays sQ(sm+0..8K, dead after Aq load) + sK(sm+8K..16K, dead after
// phase B1's QK^T/Ak reads) -> continuous KdT[t] at sm + t*128, t in [0,127].
// Extra barrier (1.5) separates sK reads (B1) from KdT writes (B2).
// Static-max softmax. XCD-swizzled blockIdx. Register prefetch pipeline (T14).
__global__ __launch_bounds__(256,4) void k_attn(const unsigned short* __restrict__ Qb,
     const unsigned short* __restrict__ Kb, const unsigned short* __restrict__ Vtb,
     const unsigned short* __restrict__ Eb, const float* __restrict__ maskp,
     float* __restrict__ out){
  __shared__ char sm[40960];
  char* sQ  = sm;            // prologue only; then KdT rows 0..63
  char* sK  = sm + 8192;     // [64][64] bf16 swz; after B1: KdT rows 64..127
  char* sVt = sm + 16384;    // [64 d][64 r] bf16 swz
  char* uni = sm + 24576;    // 16KB: sE [128 t][64 d] swz; after barrier2 QdT/sP per-wave slices
  char* sE  = uni;
  // KdT element (t,r): byte = t*128 + ((2r&~15)^((t&7)<<4)) + (2r&15)

  int tid = threadIdx.x, lane = tid&63, wid = tid>>6;
  int g = lane>>4, cl = lane&15;
  int bid = (int)blockIdx.x;
  int swz = (bid&7)*128 + (bid>>3);      // 1024 = 8 XCDs x 128 contiguous tiles
  int bh = swz>>5, lt = swz&31;
  int b = bh>>4;
  int l0 = lt*64;
  const char* Qg = (const char*)Qb  + (size_t)bh*2048*64*2;
  const char* Kg = (const char*)Kb  + (size_t)bh*2048*64*2;
  const char* Vg = (const char*)Vtb + (size_t)bh*64*2048*2;
  const float* mbase = maskp + b*2048;

  // per-thread staging coordinates (two chunks per tile)
  int rowA = tid>>3,        bcA = (tid&7)*16;        // chunk 0: rows 0..31
  int rowB = (tid+256)>>3,  bcB = bcA;               // chunk 1: rows 32..63
  int rowC = rowA+64, rowD = rowB+64;                // E rows 64..127

  // ---- prefetch st=0 tiles into registers ----
  uint4 cK0, cK1, cV0, cV1, cE0, cE1, cE2, cE3;
  float cM[4];
  {
    int t0 = l0 + 1984;
    cK0 = *(const uint4*)(Kg + ((size_t)rowA*64)*2 + bcA);
    cK1 = *(const uint4*)(Kg + ((size_t)rowB*64)*2 + bcB);
    cV0 = *(const uint4*)(Vg + ((size_t)rowA*2048)*2 + bcA);
    cV1 = *(const uint4*)(Vg + ((size_t)rowB*2048)*2 + bcB);
    cE0 = *(const uint4*)((const char*)Eb + ((size_t)(t0+rowA)*64)*2 + bcA);
    cE1 = *(const uint4*)((const char*)Eb + ((size_t)(t0+rowB)*64)*2 + bcB);
    cE2 = *(const uint4*)((const char*)Eb + ((size_t)(t0+rowC)*64)*2 + bcA);
    cE3 = *(const uint4*)((const char*)Eb + ((size_t)(t0+rowD)*64)*2 + bcB);
    for(int c=0;c<4;c++) cM[c] = mbase[c*16 + cl];
  }

  // stage Q tile once (into sQ; dead after Aq regs loaded)
  for(int it=0; it<2; it++){
    int ch = tid + it*256; int row = ch>>3; int bc = (ch&7)*16;
    uint4 v = *(const uint4*)(Qg + ((size_t)(l0+row)*64)*2 + bc);
    *(uint4*)(sQ + row*128 + (bc ^ ((row&7)<<4))) = v;
  }
  __syncthreads();
  bf16x8 Aq[2];
  { int row = wid*16 + cl;
    Aq[0] = *(const bf16x8*)(sQ + row*128 + ((g*16)      ^ ((row&7)<<4)));
    Aq[1] = *(const bf16x8*)(sQ + row*128 + ((64 + g*16) ^ ((row&7)<<4)));
  }

  f32x4 O[4] = {};
  float srow[4] = {0.f,0.f,0.f,0.f};   // per-lane partial denominator
  char* QdTs = uni + wid*4096;
  char* sPs  = uni + wid*4096;

  int swzA = bcA ^ ((rowA&7)<<4), swzB = bcB ^ ((rowB&7)<<4);
  for(int st=0; st<32; st++){
    int r0 = st*64;
    // ---- write prefetched tiles to LDS ----
    *(uint4*)(sK  + rowA*128 + swzA) = cK0;
    *(uint4*)(sK  + rowB*128 + swzB) = cK1;
    *(uint4*)(sVt + rowA*128 + swzA) = cV0;
    *(uint4*)(sVt + rowB*128 + swzB) = cV1;
    *(uint4*)(sE  + rowA*128 + swzA) = cE0;
    *(uint4*)(sE  + rowB*128 + swzB) = cE1;
    *(uint4*)(sE  + rowC*128 + swzA) = cE2;   // (rowC&7)==(rowA&7)
    *(uint4*)(sE  + rowD*128 + swzB) = cE3;
    __syncthreads();   // barrier1: tiles staged

    // local copy of current mask before prefetch overwrites cM
    float mv[4];
    for(int c=0;c<4;c++) mv[c] = cM[c];

    // ---- issue next step's global loads (hidden under phases B-D) ----
    if (st < 31){
      int r0n = r0 + 64;
      int t0n = l0 - r0n + 1984;
      cK0 = *(const uint4*)(Kg + ((size_t)(r0n+rowA)*64)*2 + bcA);
      cK1 = *(const uint4*)(Kg + ((size_t)(r0n+rowB)*64)*2 + bcB);
      cV0 = *(const uint4*)(Vg + ((size_t)(rowA*2048) + r0n)*2 + bcA);
      cV1 = *(const uint4*)(Vg + ((size_t)(rowB*2048) + r0n)*2 + bcB);
      cE0 = *(const uint4*)((const char*)Eb + ((size_t)(t0n+rowA)*64)*2 + bcA);
      cE1 = *(const uint4*)((const char*)Eb + ((size_t)(t0n+rowB)*64)*2 + bcB);
      cE2 = *(const uint4*)((const char*)Eb + ((size_t)(t0n+rowC)*64)*2 + bcA);
      cE3 = *(const uint4*)((const char*)Eb + ((size_t)(t0n+rowD)*64)*2 + bcB);
      for(int c=0;c<4;c++) cM[c] = mbase[r0n + c*16 + cl];
    }

    // ---- phase B1: QK^T + Ak (sK reads); Qd (sE reads, wave's band window) ----
    f32x4 S[4] = {};
    for(int c=0;c<4;c++){
      for(int kc=0;kc<2;kc++){
        int row = c*16 + cl;
        bf16x8 bk_ = *(const bf16x8*)(sK + row*128 + ((kc*64+g*16) ^ ((row&7)<<4)));
        S[c] = __builtin_amdgcn_mfma_f32_16x16x32_bf16(Aq[kc], bk_, S[c], 0,0,0);
      }
    }
    bf16x8 Ak[2];
    { int row = wid*16 + cl;
      Ak[0] = *(const bf16x8*)(sK + row*128 + ((g*16)    ^ ((row&7)<<4)));
      Ak[1] = *(const bf16x8*)(sK + row*128 + ((64+g*16) ^ ((row&7)<<4)));
    }
    // Qd: wave needs t in [wid*16, wid*16+78] -> c in [wid, wid+4]
    f32x4 qd[5];
    #pragma unroll
    for(int u=0;u<5;u++){
      int c = wid + u;
      int t = c*16 + cl;
      bf16x8 be0 = *(const bf16x8*)(sE + t*128 + ((g*16)    ^ ((t&7)<<4)));
      bf16x8 be1 = *(const bf16x8*)(sE + t*128 + ((64+g*16) ^ ((t&7)<<4)));
      f32x4 z = {};
      qd[u] = __builtin_amdgcn_mfma_f32_16x16x32_bf16(Aq[0], be0, z,     0,0,0);
      qd[u] = __builtin_amdgcn_mfma_f32_16x16x32_bf16(Aq[1], be1, qd[u], 0,0,0);
    }
    __syncthreads();   // barrier1.5: all sK reads done; KdT may overwrite sQ/sK

    // ---- phase B2: Kd (sE reads) -> KdT (over sQ+sK regions) ----
    // this wave's r-block [wid*16, wid*16+15] is read at t in [48-wr,126-wr] -> c in [3-wid, 7-wid]
    #pragma unroll
    for(int u=0;u<5;u++){
      int c = 3 - wid + u;
      int t = c*16 + cl;
      bf16x8 be0 = *(const bf16x8*)(sE + t*128 + ((g*16)    ^ ((t&7)<<4)));
      bf16x8 be1 = *(const bf16x8*)(sE + t*128 + ((64+g*16) ^ ((t&7)<<4)));
      f32x4 z = {};
      f32x4 kd = __builtin_amdgcn_mfma_f32_16x16x32_bf16(Ak[0], be0, z,  0,0,0);
      kd = __builtin_amdgcn_mfma_f32_16x16x32_bf16(Ak[1], be1, kd, 0,0,0);
      int bir = wid*32 + g*8;
      int addr = t*128 + (((bir & ~15) ^ ((t&7)<<4)) + (bir & 15));
      uint2 p; p.x = pk2(kd[0], kd[1]); p.y = pk2(kd[2], kd[3]);
      *(uint2*)(sm + addr) = p;
    }
    __syncthreads();   // barrier2: sE dead everywhere; KdT visible

    // ---- phase C: write QdT (over dead sE), gather rel terms, exp, accumulate ----
    #pragma unroll
    for(int u=0;u<5;u++){
      int t = (wid+u)*16 + cl;
      int addr = t*32 + ((g*8) ^ ((((t>>2)&3))<<3));
      uint2 p; p.x = pk2(qd[u][0], qd[u][1]); p.y = pk2(qd[u][2], qd[u][3]);
      *(uint2*)(QdTs + addr) = p;
    }
    float vals[4][4];
    for(int c=0;c<4;c++){
      int ri = c*16 + cl;
      #pragma unroll
      for(int r=0;r<4;r++){
        int li = wid*16 + g*4 + r;
        int idx = li - ri + 63;                 // in [0,126]
        int a1 = idx*32 + (((g*8) ^ ((((idx>>2)&3))<<3)) + r*2);
        float qv = bf2f(*(const unsigned short*)(QdTs + a1));
        int b3 = ri*2;
        int a2 = idx*128 + (((b3 & ~15) ^ ((idx&7)<<4)) + (b3 & 15));
        float kv = bf2f(*(const unsigned short*)(sm + a2));
        vals[c][r] = (S[c][r] + qv + kv)*0.125f + mv[c];
      }
    }
    #pragma unroll
    for(int r=0;r<4;r++){
      float p0 = __expf(vals[0][r]); float p1 = __expf(vals[1][r]);
      float p2 = __expf(vals[2][r]); float p3 = __expf(vals[3][r]);
      vals[0][r]=p0; vals[1][r]=p1; vals[2][r]=p2; vals[3][r]=p3;
      srow[r] += (p0+p1)+(p2+p3);
    }
    // write P (own wave slice; own QdT reads already consumed)
    for(int c=0;c<4;c++){
      #pragma unroll
      for(int r=0;r<4;r++){
        int row = g*4 + r;
        int bir = (c*16+cl)*2;
        int addr = row*128 + (((bir & ~15) ^ ((row&7)<<4)) + (bir & 15));
        *(unsigned short*)(sPs + addr) = f2bf(vals[c][r]);
      }
    }
    // ---- phase D: PV ----
    for(int kc=0;kc<2;kc++){
      int rp = cl;
      bf16x8 Ap = *(const bf16x8*)(sPs + rp*128 + ((kc*64+g*16) ^ ((rp&7)<<4)));
      for(int c=0;c<4;c++){
        int rv = c*16 + cl;
        bf16x8 Bv = *(const bf16x8*)(sVt + rv*128 + ((kc*64+g*16) ^ ((rv&7)<<4)));
        O[c] = __builtin_amdgcn_mfma_f32_16x16x32_bf16(Ap, Bv, O[c], 0,0,0);
      }
    }
    __syncthreads();   // barrier3: safe to overwrite LDS next loop-top
  }

  // epilogue: reduce denominator across the 16-lane group, divide, store fp32 [B][L][H]
  #pragma unroll
  for(int r=0;r<4;r++){
    float s = srow[r];
    s += __shfl_xor(s, 1, 64); s += __shfl_xor(s, 2, 64);
    s += __shfl_xor(s, 4, 64); s += __shfl_xor(s, 8, 64);
    srow[r] = s;
  }
  int hH = (bh&15)*64;
  for(int c=0;c<4;c++){
    #pragma unroll
    for(int r=0;r<4;r++){
      int l = l0 + wid*16 + g*4 + r;
      out[(size_t)(b*2048 + l)*1024 + hH + c*16 + cl] = O[c][r] / srow[r];
    }
  }
}

extern "C" void kernel_launch(void* const* d_in, const int* in_sizes, int n_in,
                              void* d_out, int out_size, void* d_ws, size_t ws_size,
                              hipStream_t stream){
  const float* X    = (const float*)d_in[0];
  const float* mask = (const float*)d_in[1];
  const float* Wq   = (const float*)d_in[2];
  const float* bq   = (const float*)d_in[3];
  const float* Wk   = (const float*)d_in[4];
  const float* bk   = (const float*)d_in[5];
  const float* Wv   = (const float*)d_in[6];
  const float* bv   = (const float*)d_in[7];
  const float* Ef   = (const float*)d_in[8];
  char* ws = (char*)d_ws;
  unsigned short* Xb = (unsigned short*)(ws);              // 8MB  [4096][1024]
  unsigned short* Wt = (unsigned short*)(ws + 8388608);    // 6MB  [3][1024 n][1024 k]
  unsigned short* Qb = (unsigned short*)(ws + 14680064);   // 8MB  [bh][l][d]
  unsigned short* Kb = (unsigned short*)(ws + 23068672);   // 8MB  [bh][l][d]
  unsigned short* Vt = (unsigned short*)(ws + 31457280);   // 8MB  [bh][d][l]
  unsigned short* Eb = (unsigned short*)(ws + 39845888);   // 512KB [4096][64]
  float* out = (float*)d_out;

  k_cvt_x<<<dim3(4096), dim3(256), 0, stream>>>(X, Xb);
  k_wt   <<<dim3(32,32,3), dim3(256), 0, stream>>>(Wq, Wk, Wv, Wt);
  k_cvt_e<<<dim3(256), dim3(256), 0, stream>>>(Ef, Eb);
  k_proj <<<dim3(32,24), dim3(256), 0, stream>>>(Xb, Wt, bq, bk, bv, Qb, Kb, Vt);
  k_attn <<<dim3(1024), dim3(256), 0, stream>>>(Qb, Kb, Vt, Eb, mask, out);
}

// Round 11
// 311.710 us; speedup vs baseline: 3.1260x; 3.1260x over previous
//
#include <hip/hip_runtime.h>

// Problem constants (B=2, L=2048, H=1024, NH=16, D=64, M=2048)
// scores = (Q K^T + Q·E[l-r+M-1] + K·E[l-r+M-1]) / 8 + mask; softmax; @V

typedef float f32x4 __attribute__((ext_vector_type(4)));
typedef short bf16x8 __attribute__((ext_vector_type(8)));

__device__ __forceinline__ unsigned short f2bf(float x){
  unsigned u = __float_as_uint(x);
  u += 0x7fffu + ((u>>16)&1u);           // round-to-nearest-even
  return (unsigned short)(u>>16);
}
__device__ __forceinline__ float bf2f(unsigned short s){
  return __uint_as_float(((unsigned)s)<<16);
}
__device__ __forceinline__ unsigned pk2(float a, float b){
  return (unsigned)f2bf(a) | ((unsigned)f2bf(b)<<16);
}

// ---- kernel: fp32 -> bf16 (X: 4096x1024) ----
__global__ void k_cvt_x(const float* __restrict__ x, unsigned short* __restrict__ o){
  int i = (blockIdx.x*256 + threadIdx.x)*4;
  float4 v = *(const float4*)(x + i);
  ushort4 r; r.x=f2bf(v.x); r.y=f2bf(v.y); r.z=f2bf(v.z); r.w=f2bf(v.w);
  *(ushort4*)(o + i) = r;
}

// ---- kernel: dist_emb fp32 [4095][64] -> bf16 [4096][64], row 4095 zeroed ----
__global__ void k_cvt_e(const float* __restrict__ e, unsigned short* __restrict__ o){
  int i = (blockIdx.x*256 + threadIdx.x)*4;
  ushort4 r;
  if (i < 4095*64){
    float4 v = *(const float4*)(e + i);
    r.x=f2bf(v.x); r.y=f2bf(v.y); r.z=f2bf(v.z); r.w=f2bf(v.w);
  } else { r.x=0; r.y=0; r.z=0; r.w=0; }
  *(ushort4*)(o + i) = r;
}

// ---- kernel: W [k][n] fp32 -> Wt [w][n][k] bf16 (transpose+convert) ----
__global__ void k_wt(const float* __restrict__ Wq, const float* __restrict__ Wk,
                     const float* __restrict__ Wv, unsigned short* __restrict__ wt){
  int w = blockIdx.z;
  const float* W = (w==0)?Wq:((w==1)?Wk:Wv);
  __shared__ float t[32][33];
  int k0 = blockIdx.x*32, n0 = blockIdx.y*32;
  int tx = threadIdx.x&31, ty = threadIdx.x>>5;   // ty in [0,8)
  for(int j=0;j<4;j++) t[ty+8*j][tx] = W[(k0+ty+8*j)*1024 + n0+tx];
  __syncthreads();
  unsigned short* o = wt + w*1048576;
  for(int j=0;j<4;j++) o[(n0+ty+8*j)*1024 + k0+tx] = f2bf(t[tx][ty+8*j]);
}

// ---- kernel: fused QKV projection GEMM (bf16 MFMA), 128x128 tile ----
// Q,K stored bf16 [bh][l][d]; V stored transposed bf16 [bh][d][l]
__global__ __launch_bounds__(256,2) void k_proj(const unsigned short* __restrict__ xb,
      const unsigned short* __restrict__ wt,
      const float* __restrict__ bq, const float* __restrict__ bk, const float* __restrict__ bv,
      unsigned short* __restrict__ Qo, unsigned short* __restrict__ Ko, unsigned short* __restrict__ Vt){
  __shared__ char sm[32768];
  char* sA = sm; char* sB = sm + 16384;          // [128 rows][64 k] bf16, swizzled
  int tid = threadIdx.x, lane = tid&63, wid = tid>>6;
  int g = lane>>4, cl = lane&15;
  int m0 = blockIdx.x*128;
  int wsel = blockIdx.y>>3; int n0 = (blockIdx.y&7)*128;
  const unsigned short* wp = wt + wsel*1048576;
  int wr = (wid>>1)*64, wc = (wid&1)*64;
  f32x4 acc[4][4] = {};
  for(int ks=0; ks<16; ks++){
    int k0 = ks*64;
    for(int it=0; it<4; it++){
      int ch = tid + it*256;
      int row = ch>>3; int bc = (ch&7)*16;
      uint4 va = *(const uint4*)((const char*)xb + ((size_t)(m0+row)*1024 + k0)*2 + bc);
      *(uint4*)(sA + row*128 + (bc ^ ((row&7)<<4))) = va;
      uint4 vb = *(const uint4*)((const char*)wp + ((size_t)(n0+row)*1024 + k0)*2 + bc);
      *(uint4*)(sB + row*128 + (bc ^ ((row&7)<<4))) = vb;
    }
    __syncthreads();
    for(int kc=0;kc<2;kc++){
      bf16x8 af[4], bfr[4];
      for(int i=0;i<4;i++){
        int ra = wr + i*16 + cl;
        af[i] = *(const bf16x8*)(sA + ra*128 + ((kc*64 + g*16) ^ ((ra&7)<<4)));
        int rb = wc + i*16 + cl;
        bfr[i] = *(const bf16x8*)(sB + rb*128 + ((kc*64 + g*16) ^ ((rb&7)<<4)));
      }
      for(int i=0;i<4;i++)
        for(int j=0;j<4;j++)
          acc[i][j] = __builtin_amdgcn_mfma_f32_16x16x32_bf16(af[i], bfr[j], acc[i][j], 0,0,0);
    }
    __syncthreads();
  }
  const float* bias = (wsel==0)?bq:((wsel==1)?bk:bv);
  for(int j=0;j<4;j++){
    int n = n0 + wc + j*16 + cl;
    float bb = bias[n];
    int h = n>>6, d = n&63;
    for(int i=0;i<4;i++){
      int mbase = m0 + wr + i*16 + g*4;           // 4 consecutive rows (reg 0..3)
      int b = mbase>>11; int l = mbase&2047; int bh = b*16 + h;
      if (wsel==2){
        uint2 p; p.x = pk2(acc[i][j][0]+bb, acc[i][j][1]+bb);
        p.y = pk2(acc[i][j][2]+bb, acc[i][j][3]+bb);
        *(uint2*)((char*)Vt + ((size_t)(bh*64 + d)*2048 + l)*2) = p;
      } else {
        unsigned short* O = (wsel==0)?Qo:Ko;
        for(int r=0;r<4;r++)
          O[(size_t)(bh*2048 + (l+r))*64 + d] = f2bf(acc[i][j][r]+bb);
      }
    }
  }
}

// ---- kernel: fused flash attention with relative_key_query terms ----
// grid: 1024 = bh(32) x ltile(32); block 256 (4 waves, each owns 16 l-rows)
// LDS 40KB; KdT overlays sQ+sK (dead after B1) -> KdT[t] at sm + t*128.
// launch_bounds(256,2): VGPR cap is 256/min_waves (measured: (256,2)->128,
// (256,3)->84, (256,4)->64+spill disaster). 128 VGPR = 4 waves/SIMD threshold,
// so 40KB LDS + (256,2) is the only route to 4 blocks/CU. NEVER raise.
// Static-max softmax. XCD-swizzled blockIdx. Register prefetch pipeline (T14).
__global__ __launch_bounds__(256,2) void k_attn(const unsigned short* __restrict__ Qb,
     const unsigned short* __restrict__ Kb, const unsigned short* __restrict__ Vtb,
     const unsigned short* __restrict__ Eb, const float* __restrict__ maskp,
     float* __restrict__ out){
  __shared__ char sm[40960];
  char* sQ  = sm;            // prologue only; then KdT rows 0..63
  char* sK  = sm + 8192;     // [64][64] bf16 swz; after B1: KdT rows 64..127
  char* sVt = sm + 16384;    // [64 d][64 r] bf16 swz
  char* uni = sm + 24576;    // 16KB: sE [128 t][64 d] swz; after barrier2 QdT/sP per-wave slices
  char* sE  = uni;
  // KdT element (t,r): byte = t*128 + ((2r&~15)^((t&7)<<4)) + (2r&15)

  int tid = threadIdx.x, lane = tid&63, wid = tid>>6;
  int g = lane>>4, cl = lane&15;
  int bid = (int)blockIdx.x;
  int swz = (bid&7)*128 + (bid>>3);      // 1024 = 8 XCDs x 128 contiguous tiles
  int bh = swz>>5, lt = swz&31;
  int b = bh>>4;
  int l0 = lt*64;
  const char* Qg = (const char*)Qb  + (size_t)bh*2048*64*2;
  const char* Kg = (const char*)Kb  + (size_t)bh*2048*64*2;
  const char* Vg = (const char*)Vtb + (size_t)bh*64*2048*2;
  const float* mbase = maskp + b*2048;

  // per-thread staging coordinates (two chunks per tile)
  int rowA = tid>>3,        bcA = (tid&7)*16;        // chunk 0: rows 0..31
  int rowB = (tid+256)>>3,  bcB = bcA;               // chunk 1: rows 32..63
  int rowC = rowA+64, rowD = rowB+64;                // E rows 64..127

  // ---- prefetch st=0 tiles into registers ----
  uint4 cK0, cK1, cV0, cV1, cE0, cE1, cE2, cE3;
  float cM[4];
  {
    int t0 = l0 + 1984;
    cK0 = *(const uint4*)(Kg + ((size_t)rowA*64)*2 + bcA);
    cK1 = *(const uint4*)(Kg + ((size_t)rowB*64)*2 + bcB);
    cV0 = *(const uint4*)(Vg + ((size_t)rowA*2048)*2 + bcA);
    cV1 = *(const uint4*)(Vg + ((size_t)rowB*2048)*2 + bcB);
    cE0 = *(const uint4*)((const char*)Eb + ((size_t)(t0+rowA)*64)*2 + bcA);
    cE1 = *(const uint4*)((const char*)Eb + ((size_t)(t0+rowB)*64)*2 + bcB);
    cE2 = *(const uint4*)((const char*)Eb + ((size_t)(t0+rowC)*64)*2 + bcA);
    cE3 = *(const uint4*)((const char*)Eb + ((size_t)(t0+rowD)*64)*2 + bcB);
    for(int c=0;c<4;c++) cM[c] = mbase[c*16 + cl];
  }

  // stage Q tile once (into sQ; dead after Aq regs loaded)
  for(int it=0; it<2; it++){
    int ch = tid + it*256; int row = ch>>3; int bc = (ch&7)*16;
    uint4 v = *(const uint4*)(Qg + ((size_t)(l0+row)*64)*2 + bc);
    *(uint4*)(sQ + row*128 + (bc ^ ((row&7)<<4))) = v;
  }
  __syncthreads();
  bf16x8 Aq[2];
  { int row = wid*16 + cl;
    Aq[0] = *(const bf16x8*)(sQ + row*128 + ((g*16)      ^ ((row&7)<<4)));
    Aq[1] = *(const bf16x8*)(sQ + row*128 + ((64 + g*16) ^ ((row&7)<<4)));
  }

  f32x4 O[4] = {};
  float srow[4] = {0.f,0.f,0.f,0.f};   // per-lane partial denominator
  char* QdTs = uni + wid*4096;
  char* sPs  = uni + wid*4096;

  int swzA = bcA ^ ((rowA&7)<<4), swzB = bcB ^ ((rowB&7)<<4);
  for(int st=0; st<32; st++){
    int r0 = st*64;
    // ---- write prefetched tiles to LDS ----
    *(uint4*)(sK  + rowA*128 + swzA) = cK0;
    *(uint4*)(sK  + rowB*128 + swzB) = cK1;
    *(uint4*)(sVt + rowA*128 + swzA) = cV0;
    *(uint4*)(sVt + rowB*128 + swzB) = cV1;
    *(uint4*)(sE  + rowA*128 + swzA) = cE0;
    *(uint4*)(sE  + rowB*128 + swzB) = cE1;
    *(uint4*)(sE  + rowC*128 + swzA) = cE2;   // (rowC&7)==(rowA&7)
    *(uint4*)(sE  + rowD*128 + swzB) = cE3;
    __syncthreads();   // barrier1: tiles staged

    // local copy of current mask before prefetch overwrites cM
    float mv[4];
    for(int c=0;c<4;c++) mv[c] = cM[c];

    // ---- issue next step's global loads (hidden under phases B-D) ----
    if (st < 31){
      int r0n = r0 + 64;
      int t0n = l0 - r0n + 1984;
      cK0 = *(const uint4*)(Kg + ((size_t)(r0n+rowA)*64)*2 + bcA);
      cK1 = *(const uint4*)(Kg + ((size_t)(r0n+rowB)*64)*2 + bcB);
      cV0 = *(const uint4*)(Vg + ((size_t)(rowA*2048) + r0n)*2 + bcA);
      cV1 = *(const uint4*)(Vg + ((size_t)(rowB*2048) + r0n)*2 + bcB);
      cE0 = *(const uint4*)((const char*)Eb + ((size_t)(t0n+rowA)*64)*2 + bcA);
      cE1 = *(const uint4*)((const char*)Eb + ((size_t)(t0n+rowB)*64)*2 + bcB);
      cE2 = *(const uint4*)((const char*)Eb + ((size_t)(t0n+rowC)*64)*2 + bcA);
      cE3 = *(const uint4*)((const char*)Eb + ((size_t)(t0n+rowD)*64)*2 + bcB);
      for(int c=0;c<4;c++) cM[c] = mbase[r0n + c*16 + cl];
    }

    // ---- phase B1: QK^T + Ak (sK reads); Qd (sE reads, wave's band window) ----
    f32x4 S[4] = {};
    for(int c=0;c<4;c++){
      for(int kc=0;kc<2;kc++){
        int row = c*16 + cl;
        bf16x8 bk_ = *(const bf16x8*)(sK + row*128 + ((kc*64+g*16) ^ ((row&7)<<4)));
        S[c] = __builtin_amdgcn_mfma_f32_16x16x32_bf16(Aq[kc], bk_, S[c], 0,0,0);
      }
    }
    bf16x8 Ak[2];
    { int row = wid*16 + cl;
      Ak[0] = *(const bf16x8*)(sK + row*128 + ((g*16)    ^ ((row&7)<<4)));
      Ak[1] = *(const bf16x8*)(sK + row*128 + ((64+g*16) ^ ((row&7)<<4)));
    }
    // Qd: wave needs t in [wid*16, wid*16+78] -> c in [wid, wid+4]
    f32x4 qd[5];
    #pragma unroll
    for(int u=0;u<5;u++){
      int c = wid + u;
      int t = c*16 + cl;
      bf16x8 be0 = *(const bf16x8*)(sE + t*128 + ((g*16)    ^ ((t&7)<<4)));
      bf16x8 be1 = *(const bf16x8*)(sE + t*128 + ((64+g*16) ^ ((t&7)<<4)));
      f32x4 z = {};
      qd[u] = __builtin_amdgcn_mfma_f32_16x16x32_bf16(Aq[0], be0, z,     0,0,0);
      qd[u] = __builtin_amdgcn_mfma_f32_16x16x32_bf16(Aq[1], be1, qd[u], 0,0,0);
    }
    __syncthreads();   // barrier1.5: all sK reads done; KdT may overwrite sQ/sK

    // ---- phase B2: Kd (sE reads) -> KdT (over sQ+sK regions) ----
    // this wave's r-block [wid*16, wid*16+15] is read at t in [48-wr,126-wr] -> c in [3-wid, 7-wid]
    #pragma unroll
    for(int u=0;u<5;u++){
      int c = 3 - wid + u;
      int t = c*16 + cl;
      bf16x8 be0 = *(const bf16x8*)(sE + t*128 + ((g*16)    ^ ((t&7)<<4)));
      bf16x8 be1 = *(const bf16x8*)(sE + t*128 + ((64+g*16) ^ ((t&7)<<4)));
      f32x4 z = {};
      f32x4 kd = __builtin_amdgcn_mfma_f32_16x16x32_bf16(Ak[0], be0, z,  0,0,0);
      kd = __builtin_amdgcn_mfma_f32_16x16x32_bf16(Ak[1], be1, kd, 0,0,0);
      int bir = wid*32 + g*8;
      int addr = t*128 + (((bir & ~15) ^ ((t&7)<<4)) + (bir & 15));
      uint2 p; p.x = pk2(kd[0], kd[1]); p.y = pk2(kd[2], kd[3]);
      *(uint2*)(sm + addr) = p;
    }
    __syncthreads();   // barrier2: sE dead everywhere; KdT visible

    // ---- phase C: write QdT (over dead sE), gather rel terms, exp, accumulate ----
    #pragma unroll
    for(int u=0;u<5;u++){
      int t = (wid+u)*16 + cl;
      int addr = t*32 + ((g*8) ^ ((((t>>2)&3))<<3));
      uint2 p; p.x = pk2(qd[u][0], qd[u][1]); p.y = pk2(qd[u][2], qd[u][3]);
      *(uint2*)(QdTs + addr) = p;
    }
    float vals[4][4];
    for(int c=0;c<4;c++){
      int ri = c*16 + cl;
      #pragma unroll
      for(int r=0;r<4;r++){
        int li = wid*16 + g*4 + r;
        int idx = li - ri + 63;                 // in [0,126]
        int a1 = idx*32 + (((g*8) ^ ((((idx>>2)&3))<<3)) + r*2);
        float qv = bf2f(*(const unsigned short*)(QdTs + a1));
        int b3 = ri*2;
        int a2 = idx*128 + (((b3 & ~15) ^ ((idx&7)<<4)) + (b3 & 15));
        float kv = bf2f(*(const unsigned short*)(sm + a2));
        vals[c][r] = (S[c][r] + qv + kv)*0.125f + mv[c];
      }
    }
    #pragma unroll
    for(int r=0;r<4;r++){
      float p0 = __expf(vals[0][r]); float p1 = __expf(vals[1][r]);
      float p2 = __expf(vals[2][r]); float p3 = __expf(vals[3][r]);
      vals[0][r]=p0; vals[1][r]=p1; vals[2][r]=p2; vals[3][r]=p3;
      srow[r] += (p0+p1)+(p2+p3);
    }
    // write P (own wave slice; own QdT reads already consumed)
    for(int c=0;c<4;c++){
      #pragma unroll
      for(int r=0;r<4;r++){
        int row = g*4 + r;
        int bir = (c*16+cl)*2;
        int addr = row*128 + (((bir & ~15) ^ ((row&7)<<4)) + (bir & 15));
        *(unsigned short*)(sPs + addr) = f2bf(vals[c][r]);
      }
    }
    // ---- phase D: PV ----
    for(int kc=0;kc<2;kc++){
      int rp = cl;
      bf16x8 Ap = *(const bf16x8*)(sPs + rp*128 + ((kc*64+g*16) ^ ((rp&7)<<4)));
      for(int c=0;c<4;c++){
        int rv = c*16 + cl;
        bf16x8 Bv = *(const bf16x8*)(sVt + rv*128 + ((kc*64+g*16) ^ ((rv&7)<<4)));
        O[c] = __builtin_amdgcn_mfma_f32_16x16x32_bf16(Ap, Bv, O[c], 0,0,0);
      }
    }
    __syncthreads();   // barrier3: safe to overwrite LDS next loop-top
  }

  // epilogue: reduce denominator across the 16-lane group, divide, store fp32 [B][L][H]
  #pragma unroll
  for(int r=0;r<4;r++){
    float s = srow[r];
    s += __shfl_xor(s, 1, 64); s += __shfl_xor(s, 2, 64);
    s += __shfl_xor(s, 4, 64); s += __shfl_xor(s, 8, 64);
    srow[r] = s;
  }
  int hH = (bh&15)*64;
  for(int c=0;c<4;c++){
    #pragma unroll
    for(int r=0;r<4;r++){
      int l = l0 + wid*16 + g*4 + r;
      out[(size_t)(b*2048 + l)*1024 + hH + c*16 + cl] = O[c][r] / srow[r];
    }
  }
}

extern "C" void kernel_launch(void* const* d_in, const int* in_sizes, int n_in,
                              void* d_out, int out_size, void* d_ws, size_t ws_size,
                              hipStream_t stream){
  const float* X    = (const float*)d_in[0];
  const float* mask = (const float*)d_in[1];
  const float* Wq   = (const float*)d_in[2];
  const float* bq   = (const float*)d_in[3];
  const float* Wk   = (const float*)d_in[4];
  const float* bk   = (const float*)d_in[5];
  const float* Wv   = (const float*)d_in[6];
  const float* bv   = (const float*)d_in[7];
  const float* Ef   = (const float*)d_in[8];
  char* ws = (char*)d_ws;
  unsigned short* Xb = (unsigned short*)(ws);              // 8MB  [4096][1024]
  unsigned short* Wt = (unsigned short*)(ws + 8388608);    // 6MB  [3][1024 n][1024 k]
  unsigned short* Qb = (unsigned short*)(ws + 14680064);   // 8MB  [bh][l][d]
  unsigned short* Kb = (unsigned short*)(ws + 23068672);   // 8MB  [bh][l][d]
  unsigned short* Vt = (unsigned short*)(ws + 31457280);   // 8MB  [bh][d][l]
  unsigned short* Eb = (unsigned short*)(ws + 39845888);   // 512KB [4096][64]
  float* out = (float*)d_out;

  k_cvt_x<<<dim3(4096), dim3(256), 0, stream>>>(X, Xb);
  k_wt   <<<dim3(32,32,3), dim3(256), 0, stream>>>(Wq, Wk, Wv, Wt);
  k_cvt_e<<<dim3(256), dim3(256), 0, stream>>>(Ef, Eb);
  k_proj <<<dim3(32,24), dim3(256), 0, stream>>>(Xb, Wt, bq, bk, bv, Qb, Kb, Vt);
  k_attn <<<dim3(1024), dim3(256), 0, stream>>>(Qb, Kb, Vt, Eb, mask, out);
}